// Round 2
// baseline (833.993 us; speedup 1.0000x reference)
//
#include <hip/hip_runtime.h>
#include <math.h>

#define N_ROWS 131072
#define DIMS 64
#define K_CODES 512
#define XS_STRIDE 68  // dwords; 68 % 32 == 4 -> 8 rowg-strided b128 reads hit disjoint 4-bank groups

// compile-time float4 component select (valid under full unroll)
#define COMP(v4, c) (((c)==0) ? (v4).x : (((c)==1) ? (v4).y : (((c)==2) ? (v4).z : (v4).w)))

// ---------------- K0: zero bins + c2 (numpy pairwise, bitwise) + codebook transpose ----
// cbT[d][k] = codebook[k][d], plain row-major [64][512] so 8 consecutive codes at one d
// are 32 contiguous bytes (2x global_load_dwordx4 per lane, divergent by code-group).
__global__ __launch_bounds__(256) void vq_init(const float* __restrict__ codebook,
                                               int* __restrict__ bins,
                                               float* __restrict__ c2g,
                                               float* __restrict__ cbT) {
  #pragma clang fp contract(off)
  const int t = threadIdx.x;
  const int b = blockIdx.x;
  if (b == 0) {
    for (int k = t; k < K_CODES; k += 256) bins[k] = 0;
    // numpy pairwise_sum, n=64: 8 accumulators over stride-8 lanes, then fixed tree.
    for (int k = t; k < K_CODES; k += 256) {
      const float* cr = codebook + k * DIMS;
      float r[8];
      #pragma unroll
      for (int j = 0; j < 8; ++j) r[j] = cr[j] * cr[j];
      for (int i = 8; i < 64; i += 8) {
        #pragma unroll
        for (int j = 0; j < 8; ++j) r[j] += cr[i + j] * cr[i + j];  // contract OFF: mul, add
      }
      c2g[k] = ((r[0] + r[1]) + (r[2] + r[3])) + ((r[4] + r[5]) + (r[6] + r[7]));
    }
  }
  // transpose slice: this block owns codes [b*8, b*8+8)
  for (int e = t; e < 512; e += 256) {
    const int k = b * 8 + (e >> 6);
    const int d = e & 63;
    cbT[d * K_CODES + k] = codebook[k * DIMS + d];
  }
}

// ---------------- K1: fused argmin + gather + STE + loss partial -----------------------
// Grid 2048 x 256 threads; each block does 2 tiles of 32 rows.
// Per tile: x staged in LDS (stride 68). Thread tile: R=4 rows x C=8 codes.
// lane: rowg = lane&7 (rows rowg+8i, i=0..3), codeg = lane>>3 (codes kb..kb+7).
// wave w covers codes [w*64,(w+1)*64) per half h (kb = h*256 + w*64 + codeg*8).
// Codebook read per-lane from cbT via VMEM (divergent addr -> no SMEM scalarization;
// in-order vmcnt -> compiler can pipeline). x via conflict-free ds_read_b128 broadcast.
// M = single fmaf chain over ascending d per (row,code); d2 = (x2 - 2*M) + c2.
__global__ __launch_bounds__(256, 4) void vq_main(const float* __restrict__ latents,
                                                  const float* __restrict__ codebook,
                                                  const float* __restrict__ cbT,
                                                  const float* __restrict__ c2g,
                                                  float* __restrict__ out_st,
                                                  float* __restrict__ out_codes,
                                                  int* __restrict__ bins,
                                                  double* __restrict__ loss_part) {
  #pragma clang fp contract(off)
  __shared__ __align__(16) float xs[32 * XS_STRIDE];  // 8704 B
  __shared__ float x2s[32];
  __shared__ float mvv[4][32];
  __shared__ int   mii[4][32];

  const int t = threadIdx.x;
  const int lane = t & 63;
  const int w = t >> 6;
  const int rowg = lane & 7;
  const int codeg = lane >> 3;

  double blockloss = 0.0;  // meaningful on t==0 only

  #pragma unroll 1
  for (int tile = 0; tile < 2; ++tile) {
    const int row0 = blockIdx.x * 64 + tile * 32;
    if (tile) __syncthreads();  // previous tile's dump finished reading xs

    // stage 32x64 floats coalesced -> padded LDS (512 float4, 2 per thread)
    {
      const float4* src = (const float4*)(latents + (size_t)row0 * DIMS);
      #pragma unroll
      for (int p = 0; p < 2; ++p) {
        const int f = p * 256 + t;
        *(float4*)&xs[(f >> 4) * XS_STRIDE + (f & 15) * 4] = src[f];
      }
    }
    __syncthreads();

    // x2 per row: numpy pairwise_sum (identical alg/order as before)
    if (t < 32) {
      const float* xr = xs + t * XS_STRIDE;
      float r[8];
      #pragma unroll
      for (int j = 0; j < 8; ++j) r[j] = xr[j] * xr[j];
      #pragma unroll
      for (int i = 8; i < 64; i += 8) {
        #pragma unroll
        for (int j = 0; j < 8; ++j) r[j] += xr[i + j] * xr[i + j];
      }
      x2s[t] = ((r[0] + r[1]) + (r[2] + r[3])) + ((r[4] + r[5]) + (r[6] + r[7]));
    }
    __syncthreads();

    float x2v[4];
    #pragma unroll
    for (int i = 0; i < 4; ++i) x2v[i] = x2s[rowg + 8 * i];

    float m1[4]; int i1[4];
    #pragma unroll
    for (int i = 0; i < 4; ++i) { m1[i] = __builtin_inff(); i1[i] = 0x7fffffff; }

    #pragma unroll 1
    for (int h = 0; h < 2; ++h) {
      const int kb = h * 256 + w * 64 + codeg * 8;  // per-thread ks ascend over (h, j)
      const float* cb = cbT + kb;
      float acc[4][8];
      #pragma unroll
      for (int i = 0; i < 4; ++i)
        #pragma unroll
        for (int j = 0; j < 8; ++j) acc[i][j] = 0.f;

      #pragma unroll
      for (int d4 = 0; d4 < 16; ++d4) {
        float4 xv[4];
        #pragma unroll
        for (int i = 0; i < 4; ++i)
          xv[i] = *(const float4*)&xs[(rowg + 8 * i) * XS_STRIDE + d4 * 4];
        #pragma unroll
        for (int dd = 0; dd < 4; ++dd) {
          const int d = d4 * 4 + dd;
          float cv[8];
          *(float4*)&cv[0] = *(const float4*)&cb[d * K_CODES];
          *(float4*)&cv[4] = *(const float4*)&cb[d * K_CODES + 4];
          #pragma unroll
          for (int i = 0; i < 4; ++i) {
            const float xd = COMP(xv[i], dd);  // d strictly ascending: single fmaf chain
            #pragma unroll
            for (int j = 0; j < 8; ++j) acc[i][j] = fmaf(xd, cv[j], acc[i][j]);
          }
        }
      }

      // d2 = (x2 - 2*M) + c2, one fp32 rounding per op; strict < keeps first (k ascending)
      float c2l[8];
      *(float4*)&c2l[0] = *(const float4*)&c2g[kb];
      *(float4*)&c2l[4] = *(const float4*)&c2g[kb + 4];
      #pragma unroll
      for (int j = 0; j < 8; ++j) {
        const int k = kb + j;
        #pragma unroll
        for (int i = 0; i < 4; ++i) {
          const float tt = x2v[i] - 2.0f * acc[i][j];
          const float s = tt + c2l[j];
          if (s < m1[i]) { m1[i] = s; i1[i] = k; }
        }
      }
    }

    // merge across codeg (xor 8/16/32 stays within same-rowg lane set); min val, tie->min k
    #pragma unroll
    for (int i = 0; i < 4; ++i) {
      float v = m1[i]; int idx = i1[i];
      #pragma unroll
      for (int off = 8; off < 64; off <<= 1) {
        const float ov = __shfl_xor(v, off);
        const int oi = __shfl_xor(idx, off);
        if (ov < v || (ov == v && oi < idx)) { v = ov; idx = oi; }
      }
      if (codeg == 0) { mvv[w][rowg + 8 * i] = v; mii[w][rowg + 8 * i] = idx; }
    }
    __syncthreads();

    // wave 0: cross-wave merge + fused gather/STE/loss for this tile's 32 rows
    if (w == 0) {
      double dacc = 0.0;
      if (lane < 32) {
        float v = mvv[0][lane]; int idx = mii[0][lane];
        #pragma unroll
        for (int ww = 1; ww < 4; ++ww) {
          const float ov = mvv[ww][lane]; const int oi = mii[ww][lane];
          if (ov < v || (ov == v && oi < idx)) { v = ov; idx = oi; }
        }
        out_codes[row0 + lane] = (float)idx;
        atomicAdd(&bins[idx], 1);
        const float4* crow = (const float4*)(codebook + (size_t)idx * DIMS);
        #pragma unroll
        for (int d4 = 0; d4 < 16; ++d4) {
          const float4 q = crow[d4];
          const float4 l = *(const float4*)&xs[lane * XS_STRIDE + d4 * 4];
          float4 o;
          o.x = l.x + (q.x - l.x);  // straight-through, np rounding order
          o.y = l.y + (q.y - l.y);
          o.z = l.z + (q.z - l.z);
          o.w = l.w + (q.w - l.w);
          *(float4*)&xs[lane * XS_STRIDE + d4 * 4] = o;
          const float dx = l.x - q.x, dy = l.y - q.y, dz = l.z - q.z, dw = l.w - q.w;
          dacc += (double)dx * (double)dx;
          dacc += (double)dy * (double)dy;
          dacc += (double)dz * (double)dz;
          dacc += (double)dw * (double)dw;
        }
      }
      #pragma unroll
      for (int off = 16; off > 0; off >>= 1) dacc += __shfl_down(dacc, off, 32);
      if (lane == 0) blockloss += dacc;
    }
    __syncthreads();

    // coalesced out_st dump from LDS
    {
      float4* dst = (float4*)out_st + (size_t)row0 * 16;
      #pragma unroll
      for (int p = 0; p < 2; ++p) {
        const int f = p * 256 + t;
        dst[f] = *(const float4*)&xs[(f >> 4) * XS_STRIDE + (f & 15) * 4];
      }
    }
  }
  if (t == 0) loss_part[blockIdx.x] = blockloss;
}

// ---------------- K3: reduce loss partials + perplexity + scalar outputs ----------
__global__ __launch_bounds__(512) void vq_finalize(const int* __restrict__ bins,
                                                   const double* __restrict__ loss_part,
                                                   float* __restrict__ out3) {
  __shared__ double red[512];
  __shared__ double redl[512];
  const int t = threadIdx.x;
  const double p = (double)bins[t] / 131072.0;
  red[t] = -p * log(p + 1e-10);
  redl[t] = (loss_part[t] + loss_part[t + 512]) + (loss_part[t + 1024] + loss_part[t + 1536]);
  __syncthreads();
  for (int s = 256; s > 0; s >>= 1) {
    if (t < s) { red[t] += red[t + s]; redl[t] += redl[t + s]; }
    __syncthreads();
  }
  if (t == 0) {
    const double mean = redl[0] / 8388608.0;
    out3[0] = (float)(0.25 * mean);  // commitment * COMMITMENT_COST
    out3[1] = (float)mean;           // codebook_loss (same squares bitwise)
    out3[2] = (float)exp(red[0]);    // perplexity
  }
}

extern "C" void kernel_launch(void* const* d_in, const int* in_sizes, int n_in,
                              void* d_out, int out_size, void* d_ws, size_t ws_size,
                              hipStream_t stream) {
  const float* latents = (const float*)d_in[0];
  const float* codebook = (const float*)d_in[1];

  float* out = (float*)d_out;
  float* out_st = out;                              // 8388608
  float* out_codes = out + (size_t)N_ROWS * DIMS;   // 131072 (codes as float)
  float* out3 = out_codes + N_ROWS;                 // 3 scalars

  char* ws = (char*)d_ws;
  double* loss_part = (double*)ws;                  // [0, 16384)        2048 doubles
  int* bins = (int*)(ws + 16384);                   // [16384, 18432)
  float* c2g = (float*)(ws + 18432);                // [18432, 20480)
  float* cbT = (float*)(ws + 20480);                // [20480, 151552)   128 KB transposed

  hipLaunchKernelGGL(vq_init, dim3(64), dim3(256), 0, stream,
                     codebook, bins, c2g, cbT);
  hipLaunchKernelGGL(vq_main, dim3(2048), dim3(256), 0, stream,
                     latents, codebook, cbT, c2g, out_st, out_codes, bins, loss_part);
  hipLaunchKernelGGL(vq_finalize, dim3(1), dim3(512), 0, stream,
                     bins, loss_part, out3);
}

// Round 3
// 224.188 us; speedup vs baseline: 3.7201x; 3.7201x over previous
//
#include <hip/hip_runtime.h>
#include <math.h>

#define N_ROWS 131072
#define DIMS 64
#define K_CODES 512
#define XS_STRIDE 68  // dwords; (rowg*68)%32 = 4*rowg -> 8 rowg b128 reads cover all 32 banks

// compile-time float4 component select (valid under full unroll)
#define COMP(v4, c) (((c)==0) ? (v4).x : (((c)==1) ? (v4).y : (((c)==2) ? (v4).z : (v4).w)))

// ---------------- K0: zero bins + c2 (numpy pairwise, bitwise) + codebook transpose ----
// cbT[d][k] = codebook[k][d], row-major [64][512]: 8 consecutive codes at one d are
// 32 contiguous bytes -> per-lane divergent dwordx4 loads (no SMEM scalarization).
__global__ __launch_bounds__(256) void vq_init(const float* __restrict__ codebook,
                                               int* __restrict__ bins,
                                               float* __restrict__ c2g,
                                               float* __restrict__ cbT) {
  #pragma clang fp contract(off)
  const int t = threadIdx.x;
  const int b = blockIdx.x;
  if (b == 0) {
    for (int k = t; k < K_CODES; k += 256) bins[k] = 0;
    // numpy pairwise_sum, n=64: 8 accumulators over stride-8 lanes, then fixed tree.
    for (int k = t; k < K_CODES; k += 256) {
      const float* cr = codebook + k * DIMS;
      float r[8];
      #pragma unroll
      for (int j = 0; j < 8; ++j) r[j] = cr[j] * cr[j];
      for (int i = 8; i < 64; i += 8) {
        #pragma unroll
        for (int j = 0; j < 8; ++j) r[j] += cr[i + j] * cr[i + j];  // contract OFF: mul, add
      }
      c2g[k] = ((r[0] + r[1]) + (r[2] + r[3])) + ((r[4] + r[5]) + (r[6] + r[7]));
    }
  }
  // transpose slice: this block owns codes [b*8, b*8+8)
  for (int e = t; e < 512; e += 256) {
    const int k = b * 8 + (e >> 6);
    const int d = e & 63;
    cbT[d * K_CODES + k] = codebook[k * DIMS + d];
  }
}

// ---------------- K1: fused argmin + gather + STE + loss partial -----------------------
// Grid 2048 x 256; each block does 2 tiles of 32 rows.
// Thread tile R=4 rows x C=8 codes. lane: rowg=lane&7 (rows rowg+8i), codeg=lane>>3.
// x via conflict-free LDS b128 broadcast; codebook via per-lane VMEM from L2-resident cbT.
// d4 loop is NOT unrolled (unroll 1): per iter 12 loads then 128 fmaf -> bounded VGPR,
// no scratch spill; 4 waves/SIMD hide the ~200cy L2 latency.
// M = single fmaf chain over ascending d per (row,code); d2 = (x2 - 2*M) + c2.
__global__ __launch_bounds__(256, 4) void vq_main(const float* __restrict__ latents,
                                                  const float* __restrict__ codebook,
                                                  const float* __restrict__ cbT,
                                                  const float* __restrict__ c2g,
                                                  float* __restrict__ out_st,
                                                  float* __restrict__ out_codes,
                                                  int* __restrict__ bins,
                                                  double* __restrict__ loss_part) {
  #pragma clang fp contract(off)
  __shared__ __align__(16) float xs[32 * XS_STRIDE];  // 8704 B
  __shared__ float x2s[32];
  __shared__ float mvv[4][32];
  __shared__ int   mii[4][32];

  const int t = threadIdx.x;
  const int lane = t & 63;
  const int w = t >> 6;
  const int rowg = lane & 7;
  const int codeg = lane >> 3;

  double blockloss = 0.0;  // meaningful on t==0 only

  #pragma unroll 1
  for (int tile = 0; tile < 2; ++tile) {
    const int row0 = blockIdx.x * 64 + tile * 32;
    if (tile) __syncthreads();  // previous tile's dump finished reading xs

    // stage 32x64 floats coalesced -> padded LDS (512 float4, 2 per thread)
    {
      const float4* src = (const float4*)(latents + (size_t)row0 * DIMS);
      #pragma unroll
      for (int p = 0; p < 2; ++p) {
        const int f = p * 256 + t;
        *(float4*)&xs[(f >> 4) * XS_STRIDE + (f & 15) * 4] = src[f];
      }
    }
    __syncthreads();

    // x2 per row: numpy pairwise_sum (identical alg/order as before)
    if (t < 32) {
      const float* xr = xs + t * XS_STRIDE;
      float r[8];
      #pragma unroll
      for (int j = 0; j < 8; ++j) r[j] = xr[j] * xr[j];
      #pragma unroll
      for (int i = 8; i < 64; i += 8) {
        #pragma unroll
        for (int j = 0; j < 8; ++j) r[j] += xr[i + j] * xr[i + j];
      }
      x2s[t] = ((r[0] + r[1]) + (r[2] + r[3])) + ((r[4] + r[5]) + (r[6] + r[7]));
    }
    __syncthreads();

    float x2v[4];
    #pragma unroll
    for (int i = 0; i < 4; ++i) x2v[i] = x2s[rowg + 8 * i];

    float m1[4]; int i1[4];
    #pragma unroll
    for (int i = 0; i < 4; ++i) { m1[i] = __builtin_inff(); i1[i] = 0x7fffffff; }

    #pragma unroll 1
    for (int h = 0; h < 2; ++h) {
      const int kb = h * 256 + w * 64 + codeg * 8;  // per-thread ks ascend over (h, j)
      const float4* cb4 = (const float4*)(cbT + kb);  // row d: cb4[d*128], cb4[d*128+1]
      float acc[4][8];
      #pragma unroll
      for (int i = 0; i < 4; ++i)
        #pragma unroll
        for (int j = 0; j < 8; ++j) acc[i][j] = 0.f;

      #pragma unroll 1
      for (int d4 = 0; d4 < 16; ++d4) {
        // issue all 12 loads for this iteration up front (bounded in-flight set)
        float4 xv0 = *(const float4*)&xs[(rowg +  0) * XS_STRIDE + d4 * 4];
        float4 xv1 = *(const float4*)&xs[(rowg +  8) * XS_STRIDE + d4 * 4];
        float4 xv2 = *(const float4*)&xs[(rowg + 16) * XS_STRIDE + d4 * 4];
        float4 xv3 = *(const float4*)&xs[(rowg + 24) * XS_STRIDE + d4 * 4];
        float4 c0a = cb4[(d4 * 4 + 0) * 128], c0b = cb4[(d4 * 4 + 0) * 128 + 1];
        float4 c1a = cb4[(d4 * 4 + 1) * 128], c1b = cb4[(d4 * 4 + 1) * 128 + 1];
        float4 c2a = cb4[(d4 * 4 + 2) * 128], c2b = cb4[(d4 * 4 + 2) * 128 + 1];
        float4 c3a = cb4[(d4 * 4 + 3) * 128], c3b = cb4[(d4 * 4 + 3) * 128 + 1];

        #pragma unroll
        for (int dd = 0; dd < 4; ++dd) {  // d = d4*4+dd strictly ascending: one fmaf chain
          const float4 ca = (dd == 0) ? c0a : (dd == 1) ? c1a : (dd == 2) ? c2a : c3a;
          const float4 cbv = (dd == 0) ? c0b : (dd == 1) ? c1b : (dd == 2) ? c2b : c3b;
          #pragma unroll
          for (int i = 0; i < 4; ++i) {
            const float4 xvi = (i == 0) ? xv0 : (i == 1) ? xv1 : (i == 2) ? xv2 : xv3;
            const float xd = COMP(xvi, dd);
            acc[i][0] = fmaf(xd, ca.x,  acc[i][0]);
            acc[i][1] = fmaf(xd, ca.y,  acc[i][1]);
            acc[i][2] = fmaf(xd, ca.z,  acc[i][2]);
            acc[i][3] = fmaf(xd, ca.w,  acc[i][3]);
            acc[i][4] = fmaf(xd, cbv.x, acc[i][4]);
            acc[i][5] = fmaf(xd, cbv.y, acc[i][5]);
            acc[i][6] = fmaf(xd, cbv.z, acc[i][6]);
            acc[i][7] = fmaf(xd, cbv.w, acc[i][7]);
          }
        }
      }

      // d2 = (x2 - 2*M) + c2, one fp32 rounding per op; strict < keeps first (k ascending)
      const float4 e0 = *(const float4*)&c2g[kb];
      const float4 e1 = *(const float4*)&c2g[kb + 4];
      #pragma unroll
      for (int j = 0; j < 8; ++j) {
        const float c2v = (j < 4) ? COMP(e0, j & 3) : COMP(e1, j & 3);
        const int k = kb + j;
        #pragma unroll
        for (int i = 0; i < 4; ++i) {
          const float tt = x2v[i] - 2.0f * acc[i][j];
          const float s = tt + c2v;
          if (s < m1[i]) { m1[i] = s; i1[i] = k; }
        }
      }
    }

    // merge across codeg (xor 8/16/32 stays within same-rowg lane set); min val, tie->min k
    #pragma unroll
    for (int i = 0; i < 4; ++i) {
      float v = m1[i]; int idx = i1[i];
      #pragma unroll
      for (int off = 8; off < 64; off <<= 1) {
        const float ov = __shfl_xor(v, off);
        const int oi = __shfl_xor(idx, off);
        if (ov < v || (ov == v && oi < idx)) { v = ov; idx = oi; }
      }
      if (codeg == 0) { mvv[w][rowg + 8 * i] = v; mii[w][rowg + 8 * i] = idx; }
    }
    __syncthreads();

    // wave 0: cross-wave merge + fused gather/STE/loss for this tile's 32 rows
    if (w == 0) {
      double dacc = 0.0;
      if (lane < 32) {
        float v = mvv[0][lane]; int idx = mii[0][lane];
        #pragma unroll
        for (int ww = 1; ww < 4; ++ww) {
          const float ov = mvv[ww][lane]; const int oi = mii[ww][lane];
          if (ov < v || (ov == v && oi < idx)) { v = ov; idx = oi; }
        }
        out_codes[row0 + lane] = (float)idx;
        atomicAdd(&bins[idx], 1);
        const float4* crow = (const float4*)(codebook + (size_t)idx * DIMS);
        #pragma unroll
        for (int d4 = 0; d4 < 16; ++d4) {
          const float4 q = crow[d4];
          const float4 l = *(const float4*)&xs[lane * XS_STRIDE + d4 * 4];
          float4 o;
          o.x = l.x + (q.x - l.x);  // straight-through, np rounding order
          o.y = l.y + (q.y - l.y);
          o.z = l.z + (q.z - l.z);
          o.w = l.w + (q.w - l.w);
          *(float4*)&xs[lane * XS_STRIDE + d4 * 4] = o;
          const float dx = l.x - q.x, dy = l.y - q.y, dz = l.z - q.z, dw = l.w - q.w;
          dacc += (double)dx * (double)dx;
          dacc += (double)dy * (double)dy;
          dacc += (double)dz * (double)dz;
          dacc += (double)dw * (double)dw;
        }
      }
      #pragma unroll
      for (int off = 16; off > 0; off >>= 1) dacc += __shfl_down(dacc, off, 32);
      if (lane == 0) blockloss += dacc;
    }
    __syncthreads();

    // coalesced out_st dump from LDS
    {
      float4* dst = (float4*)out_st + (size_t)row0 * 16;
      #pragma unroll
      for (int p = 0; p < 2; ++p) {
        const int f = p * 256 + t;
        dst[f] = *(const float4*)&xs[(f >> 4) * XS_STRIDE + (f & 15) * 4];
      }
    }
  }
  if (t == 0) loss_part[blockIdx.x] = blockloss;
}

// ---------------- K3: reduce loss partials + perplexity + scalar outputs ----------
__global__ __launch_bounds__(512) void vq_finalize(const int* __restrict__ bins,
                                                   const double* __restrict__ loss_part,
                                                   float* __restrict__ out3) {
  __shared__ double red[512];
  __shared__ double redl[512];
  const int t = threadIdx.x;
  const double p = (double)bins[t] / 131072.0;
  red[t] = -p * log(p + 1e-10);
  redl[t] = (loss_part[t] + loss_part[t + 512]) + (loss_part[t + 1024] + loss_part[t + 1536]);
  __syncthreads();
  for (int s = 256; s > 0; s >>= 1) {
    if (t < s) { red[t] += red[t + s]; redl[t] += redl[t + s]; }
    __syncthreads();
  }
  if (t == 0) {
    const double mean = redl[0] / 8388608.0;
    out3[0] = (float)(0.25 * mean);  // commitment * COMMITMENT_COST
    out3[1] = (float)mean;           // codebook_loss (same squares bitwise)
    out3[2] = (float)exp(red[0]);    // perplexity
  }
}

extern "C" void kernel_launch(void* const* d_in, const int* in_sizes, int n_in,
                              void* d_out, int out_size, void* d_ws, size_t ws_size,
                              hipStream_t stream) {
  const float* latents = (const float*)d_in[0];
  const float* codebook = (const float*)d_in[1];

  float* out = (float*)d_out;
  float* out_st = out;                              // 8388608
  float* out_codes = out + (size_t)N_ROWS * DIMS;   // 131072 (codes as float)
  float* out3 = out_codes + N_ROWS;                 // 3 scalars

  char* ws = (char*)d_ws;
  double* loss_part = (double*)ws;                  // [0, 16384)        2048 doubles
  int* bins = (int*)(ws + 16384);                   // [16384, 18432)
  float* c2g = (float*)(ws + 18432);                // [18432, 20480)
  float* cbT = (float*)(ws + 20480);                // [20480, 151552)   128 KB transposed

  hipLaunchKernelGGL(vq_init, dim3(64), dim3(256), 0, stream,
                     codebook, bins, c2g, cbT);
  hipLaunchKernelGGL(vq_main, dim3(2048), dim3(256), 0, stream,
                     latents, codebook, cbT, c2g, out_st, out_codes, bins, loss_part);
  hipLaunchKernelGGL(vq_finalize, dim3(1), dim3(512), 0, stream,
                     bins, loss_part, out3);
}